// Round 2
// baseline (347.069 us; speedup 1.0000x reference)
//
#include <hip/hip_runtime.h>
#include <hip/hip_bf16.h>

typedef __bf16 bf16_t;
typedef __bf16 bf16x8 __attribute__((ext_vector_type(8)));
typedef float f32x4 __attribute__((ext_vector_type(4)));

#define MFMA16(A, B, C) __builtin_amdgcn_mfma_f32_16x16x32_bf16(A, B, C, 0, 0, 0)

// load 8 consecutive f32 (32B, 16B-aligned) and round to bf16x8 (RNE)
__device__ __forceinline__ bf16x8 load_cvt8(const float* __restrict__ p) {
    f32x4 a = *(const f32x4*)p;
    f32x4 b = *(const f32x4*)(p + 4);
    bf16x8 r;
    r[0] = (bf16_t)a[0]; r[1] = (bf16_t)a[1]; r[2] = (bf16_t)a[2]; r[3] = (bf16_t)a[3];
    r[4] = (bf16_t)b[0]; r[5] = (bf16_t)b[1]; r[6] = (bf16_t)b[2]; r[7] = (bf16_t)b[3];
    return r;
}

// H=8, B=256, L=128, D=64. One block per (h,b). 4 waves; wave w owns Q rows [32w,32w+32).
// fp32 global I/O; bf16 MFMA internally (QK^T and PV), fp32 softmax.
__global__ __launch_bounds__(256, 2)
void sdpa_kernel(const float* __restrict__ q, const float* __restrict__ kmat,
                 const float* __restrict__ v, const float* __restrict__ bias,
                 float* __restrict__ out, float* __restrict__ attn)
{
    constexpr int L = 128, D = 64;
    constexpr int PS = 136;  // P LDS stride (128+8): keeps b128 16B-aligned
    constexpr int VS = 136;  // Vt LDS stride
    __shared__ __align__(16) bf16_t Pl[L * PS];   // 34816 B
    __shared__ __align__(16) bf16_t Vt[D * VS];   // 17408 B (XOR-granule swizzled)

    const int bh   = blockIdx.x;        // h*256 + b
    const int h    = bh >> 8;
    const int tid  = threadIdx.x;
    const int w    = tid >> 6;          // wave 0..3
    const int lane = tid & 63;
    const int g    = lane >> 4;         // quad 0..3
    const int c    = lane & 15;

    const float* qb = q    + (size_t)bh * (L * D);
    const float* kb = kmat + (size_t)bh * (L * D);
    const float* vb = v    + (size_t)bh * (L * D);
    const float* bb = bias + (size_t)h  * (L * L);
    float* outb  = out  + (size_t)bh * (L * D);
    float* attnb = attn + (size_t)bh * (L * L);

    // ---- V -> registers, coalesced 32B/lane. thread t holds V[t/8 + 32it][(t%8)*8 .. +8)
    f32x4 vreg[4][2];
#pragma unroll
    for (int it = 0; it < 4; ++it) {
        const float* p = vb + tid * 8 + it * 2048;
        vreg[it][0] = *(const f32x4*)p;
        vreg[it][1] = *(const f32x4*)(p + 4);
    }

    // ---- Q A-fragments straight from global: A[m=c][k = kk*32 + g*8 + j], rows 32w+16rt+c
    bf16x8 qf[2][2];
#pragma unroll
    for (int rt = 0; rt < 2; ++rt)
#pragma unroll
        for (int kk = 0; kk < 2; ++kk)
            qf[rt][kk] = load_cvt8(qb + (32 * w + 16 * rt + c) * D + kk * 32 + g * 8);

    // ---- S = Q K^T (2 row-tiles x 8 col-tiles of 16x16, K=64 in 2 steps)
    f32x4 acc[2][8];
#pragma unroll
    for (int rt = 0; rt < 2; ++rt)
#pragma unroll
        for (int ct = 0; ct < 8; ++ct)
            acc[rt][ct] = f32x4{0.f, 0.f, 0.f, 0.f};

#pragma unroll
    for (int ct = 0; ct < 8; ++ct) {
        // B[k][n] = K[n][k]: lane reads K row n=16ct+c, 32B contiguous per half
        bf16x8 kf0 = load_cvt8(kb + (16 * ct + c) * D + g * 8);
        bf16x8 kf1 = load_cvt8(kb + (16 * ct + c) * D + 32 + g * 8);
        acc[0][ct] = MFMA16(qf[0][0], kf0, acc[0][ct]);
        acc[0][ct] = MFMA16(qf[0][1], kf1, acc[0][ct]);
        acc[1][ct] = MFMA16(qf[1][0], kf0, acc[1][ct]);
        acc[1][ct] = MFMA16(qf[1][1], kf1, acc[1][ct]);
    }

    // ---- stage V transposed into LDS (bf16) with XOR-granule swizzle:
    // Vt element (d,k) at d*VS + ((k>>3) ^ ((d>>3)&7))*8 + (k&7)
    {
        const int p = tid & 7, sl = tid >> 3;   // d-octet, k-row
#pragma unroll
        for (int it = 0; it < 4; ++it) {
            const int base = (((sl >> 3) + 4 * it) ^ p) * 8 + (sl & 7);
#pragma unroll
            for (int j = 0; j < 8; ++j)
                Vt[(8 * p + j) * VS + base] = (bf16_t)vreg[it][j >> 2][j & 3];
        }
    }

    // ---- softmax: row held by the 16 lanes sharing g; 8 in-lane vals + shfl_xor {1,2,4,8}
#pragma unroll
    for (int rt = 0; rt < 2; ++rt) {
#pragma unroll
        for (int r = 0; r < 4; ++r) {
            const int row = 32 * w + 16 * rt + 4 * g + r;
            float s[8], m = -1e30f;
#pragma unroll
            for (int ct = 0; ct < 8; ++ct) {
                const float bv = bb[row * L + 16 * ct + c];
                s[ct] = acc[rt][ct][r] * 0.125f + bv;   // /TEMPERATURE + pos_bias
                m = fmaxf(m, s[ct]);
            }
            m = fmaxf(m, __shfl_xor(m, 1));
            m = fmaxf(m, __shfl_xor(m, 2));
            m = fmaxf(m, __shfl_xor(m, 4));
            m = fmaxf(m, __shfl_xor(m, 8));
            float sum = 0.f;
#pragma unroll
            for (int ct = 0; ct < 8; ++ct) {
                s[ct] = exp2f((s[ct] - m) * 1.4426950408889634f);
                sum += s[ct];
            }
            sum += __shfl_xor(sum, 1);
            sum += __shfl_xor(sum, 2);
            sum += __shfl_xor(sum, 4);
            sum += __shfl_xor(sum, 8);
            const float inv = 1.0f / sum;
#pragma unroll
            for (int ct = 0; ct < 8; ++ct)
                acc[rt][ct][r] = s[ct] * inv;
        }
    }

    // ---- P -> LDS (bf16, C-layout scatter)
#pragma unroll
    for (int rt = 0; rt < 2; ++rt)
#pragma unroll
        for (int r = 0; r < 4; ++r) {
            const int row = 32 * w + 16 * rt + 4 * g + r;
#pragma unroll
            for (int ct = 0; ct < 8; ++ct)
                Pl[row * PS + 16 * ct + c] = (bf16_t)acc[rt][ct][r];
        }

    __syncthreads();

    // ---- P -> attn global as f32, coalesced float4 stores (4096 chunks of 4 elems)
#pragma unroll
    for (int i = 0; i < 16; ++i) {
        const int c4  = tid + 256 * i;
        const int row = c4 >> 5, seg = c4 & 31;
        const bf16_t* p = &Pl[row * PS + seg * 4];
        f32x4 o;
        o[0] = (float)p[0]; o[1] = (float)p[1]; o[2] = (float)p[2]; o[3] = (float)p[3];
        *(f32x4*)(attnb + row * L + seg * 4) = o;
    }

    // ---- out = P V   (2 row-tiles x 4 col-tiles, K=128 in 4 steps)
    f32x4 oacc[2][4];
#pragma unroll
    for (int rt = 0; rt < 2; ++rt)
#pragma unroll
        for (int ct = 0; ct < 4; ++ct)
            oacc[rt][ct] = f32x4{0.f, 0.f, 0.f, 0.f};

#pragma unroll
    for (int kk = 0; kk < 4; ++kk) {
        const bf16x8 pa0 = *(const bf16x8*)(&Pl[(32 * w + c) * PS + 32 * kk + 8 * g]);
        const bf16x8 pa1 = *(const bf16x8*)(&Pl[(32 * w + 16 + c) * PS + 32 * kk + 8 * g]);
#pragma unroll
        for (int ct = 0; ct < 4; ++ct) {
            const int n = 16 * ct + c;   // V column = out column
            const bf16x8 vf =
                *(const bf16x8*)(&Vt[n * VS + (((4 * kk + g) ^ ((n >> 3) & 7)) * 8)]);
            oacc[0][ct] = MFMA16(pa0, vf, oacc[0][ct]);
            oacc[1][ct] = MFMA16(pa1, vf, oacc[1][ct]);
        }
    }

    // ---- out stores (f32 scalar; 4x64B segments/instr, L2 write-combines)
#pragma unroll
    for (int rt = 0; rt < 2; ++rt)
#pragma unroll
        for (int ct = 0; ct < 4; ++ct)
#pragma unroll
            for (int r = 0; r < 4; ++r) {
                const int row = 32 * w + 16 * rt + 4 * g + r;
                outb[row * D + 16 * ct + c] = oacc[rt][ct][r];
            }
}

extern "C" void kernel_launch(void* const* d_in, const int* in_sizes, int n_in,
                              void* d_out, int out_size, void* d_ws, size_t ws_size,
                              hipStream_t stream) {
    const float* q  = (const float*)d_in[0];
    const float* k  = (const float*)d_in[1];
    const float* v  = (const float*)d_in[2];
    const float* pb = (const float*)d_in[3];
    float* out  = (float*)d_out;
    float* attn = out + (size_t)8 * 256 * 128 * 64;   // outputs concatenated: out then attn
    sdpa_kernel<<<dim3(8 * 256), dim3(256), 0, stream>>>(q, k, v, pb, out, attn);
}